// Round 12
// baseline (266.214 us; speedup 1.0000x reference)
//
#include <hip/hip_runtime.h>

#define Bb 32
#define Ss 2048
#define Hh 1024

typedef __attribute__((ext_vector_type(4))) float f32x4;
typedef __attribute__((ext_vector_type(8))) short s16x8;

#define GAS const __attribute__((address_space(1))) unsigned int
#define LAS __attribute__((address_space(3))) unsigned int

__device__ __forceinline__ unsigned short f2bf(float x) {
  unsigned int u = __float_as_uint(x);
  u = (u + 0x7fffu + ((u >> 16) & 1u)) >> 16;
  return (unsigned short)u;
}

// W_enc fp32 [1024][1024] -> bf16, tiled+inverse-swizzled (R8-verified layout):
// half = ((row>>8)*16 + kt)*2 + kh (16KB); byte = (row&255)*64 + ((k4^((r>>1)&3))<<4)
__global__ void cvt_w(const float* __restrict__ in, unsigned short* __restrict__ out) {
  int g = blockIdx.x * blockDim.x + threadIdx.x;
  int row = g >> 7, k8 = g & 127;
  const float4* src = reinterpret_cast<const float4*>(in + (size_t)row * Hh + k8 * 8);
  float4 a = src[0], b = src[1];
  union { unsigned short u[8]; uint4 q; } rr;
  rr.u[0] = f2bf(a.x); rr.u[1] = f2bf(a.y); rr.u[2] = f2bf(a.z); rr.u[3] = f2bf(a.w);
  rr.u[4] = f2bf(b.x); rr.u[5] = f2bf(b.y); rr.u[6] = f2bf(b.z); rr.u[7] = f2bf(b.w);
  int kt = k8 >> 3, kh = (k8 >> 2) & 1, k4 = k8 & 3;
  int r = row & 255;
  size_t byte = (size_t)(((row >> 8) * 16 + kt) * 2 + kh) * 16384
              + (size_t)(r * 64 + ((k4 ^ ((r >> 1) & 3)) << 4));
  *reinterpret_cast<uint4*>(reinterpret_cast<char*>(out) + byte) = rr.q;
}

// ---- dec_feature[b][o] = dot(dh[b], W_dec[o]) + b_dec[o] ----
__global__ void dec_feat_kernel(const float* __restrict__ dh,
                                const float* __restrict__ Wd,
                                const float* __restrict__ bd,
                                float* __restrict__ out) {
  int gw = blockIdx.x * 4 + (threadIdx.x >> 6);
  int lane = threadIdx.x & 63;
  int b = gw >> 10, o = gw & 1023;
  const float4* x = reinterpret_cast<const float4*>(dh + (size_t)b * Hh);
  const float4* w = reinterpret_cast<const float4*>(Wd + (size_t)o * Hh);
  float acc = 0.f;
#pragma unroll
  for (int it = 0; it < 4; ++it) {
    float4 xa = x[lane + it * 64];
    float4 wa = w[lane + it * 64];
    acc += xa.x * wa.x + xa.y * wa.y + xa.z * wa.z + xa.w * wa.w;
  }
#pragma unroll
  for (int m = 1; m < 64; m <<= 1) acc += __shfl_xor(acc, m, 64);
  if (lane == 0) out[gw] = acc + bd[o];
}

// ---- 8-phase 256x256 GEMM, B-frag reuse (R11) + A reg-staged fp32->bf16 with
// conflict-free write map (read-map geometry: 8 consecutive lanes span 32 banks).
// 512 thr = 8 waves (2M x 4N), BK=64, 16 K-tiles, buf c = t&1.
// LDS buf: A-kh0 @0, A-kh1 @16K, B-kh0 @32K, B-kh1 @48K (64KB x 2).
__global__ void __launch_bounds__(512, 2)
gemm8v(const float* __restrict__ A,            // enc fp32 [65536][1024]
       const unsigned short* __restrict__ Bw,  // W_bf tiled/swizzled
       const float* __restrict__ decf,         // [32,1024]
       const float* __restrict__ cov,          // [32,2048]
       const float* __restrict__ wcov,         // [1024]
       const float* __restrict__ v,            // [1024]
       float* __restrict__ part) {             // [16][65536] partials (ot*4+wn)
  __shared__ char lds[131072];

  const int bid = blockIdx.x;
  const int swz = (bid & 7) * 128 + (bid >> 3);  // bijective: 1024 % 8 == 0
  const int s_tile = swz >> 2;  // 0..255 ; ot fast -> A-panel L2 reuse within XCD
  const int ot = swz & 3;       // 0..3

  const int tid = threadIdx.x, lane = tid & 63, wid = tid >> 6;
  const int wm = wid >> 2, wn = wid & 3;     // per-wave out: 128 x 64
  const int fr = lane & 15, hi = lane >> 4;

  // A reg staging (conflict-free map): lane handles row w*32+q*16+(lane&15),
  // k-group lane>>4; stored slot = (lane>>4) ^ ((lane>>1)&3)  [row bits 1:2 = lane 1:2]
  const int arow = wid * 32 + (lane & 15);   // local row (q adds 16)
  const float* gA0 = A + (size_t)(s_tile * 256 + arow) * 1024 + (lane >> 4) * 8;
  const int awbyte = arow * 64 + (((lane >> 4) ^ ((lane >> 1) & 3)) << 4);

  const char* gB = reinterpret_cast<const char*>(Bw) + (size_t)ot * 524288 + tid * 16;

  const int xslot = (hi ^ ((fr >> 1) & 3)) << 4;
  const int aRow = (wm * 128 + fr) * 64;            // + mh*4096 + fm*1024 + xslot
  const int bRow = 32768 + (wn * 64 + fr) * 64;     // + fn*1024 + xslot

  f32x4 acc[8][4];
#pragma unroll
  for (int i = 0; i < 8; ++i)
#pragma unroll
    for (int j = 0; j < 4; ++j) acc[i][j] = (f32x4){0.f, 0.f, 0.f, 0.f};

  float4 a0, a1, a2, a3, a4, a5, a6, a7;  // (q,h,lo/hi): a0,a1=q0h0 a2,a3=q1h0 a4..=h1

#define ISSUE_H0(kt) do { const float* _p = gA0 + (size_t)(kt) * 64;              \
    a0 = *reinterpret_cast<const float4*>(_p);                                    \
    a1 = *reinterpret_cast<const float4*>(_p + 4);                                \
    a2 = *reinterpret_cast<const float4*>(_p + 16384);                            \
    a3 = *reinterpret_cast<const float4*>(_p + 16388); } while (0)
#define ISSUE_H1(kt) do { const float* _p = gA0 + (size_t)(kt) * 64 + 32;         \
    a4 = *reinterpret_cast<const float4*>(_p);                                    \
    a5 = *reinterpret_cast<const float4*>(_p + 4);                                \
    a6 = *reinterpret_cast<const float4*>(_p + 16384);                            \
    a7 = *reinterpret_cast<const float4*>(_p + 16388); } while (0)

#define STAGE_B(t2, kh, c2) do {                                                  \
    const char* _s = gB + (size_t)((t2) * 2 + (kh)) * 16384;                      \
    char* _d = lds + (c2) * 65536 + 32768 + (kh) * 16384 + tid * 16;              \
    __builtin_amdgcn_global_load_lds((GAS*)(_s),        (LAS*)(_d),        16, 0, 0); \
    __builtin_amdgcn_global_load_lds((GAS*)(_s + 8192), (LAS*)(_d + 8192), 16, 0, 0); \
  } while (0)

#define AW1(c, qoff, hoff, xa, xb) do {                                           \
    union { unsigned short u[8]; uint4 q; } _w;                                   \
    _w.u[0] = f2bf((xa).x); _w.u[1] = f2bf((xa).y);                               \
    _w.u[2] = f2bf((xa).z); _w.u[3] = f2bf((xa).w);                               \
    _w.u[4] = f2bf((xb).x); _w.u[5] = f2bf((xb).y);                               \
    _w.u[6] = f2bf((xb).z); _w.u[7] = f2bf((xb).w);                               \
    *reinterpret_cast<uint4*>(lds + (c) * 65536 + (hoff) + (qoff) + awbyte) = _w.q; \
  } while (0)
#define AWRITE(c) do { AW1(c, 0, 0, a0, a1);     AW1(c, 1024, 0, a2, a3);         \
                       AW1(c, 0, 16384, a4, a5); AW1(c, 1024, 16384, a6, a7); } while (0)

#define NW ((void)0)
#define VM8 asm volatile("s_waitcnt vmcnt(8)" ::: "memory")
#define VM4 asm volatile("s_waitcnt vmcnt(4)" ::: "memory")
#define VM0 asm volatile("s_waitcnt vmcnt(0)" ::: "memory")

  s16x8 bfr[4];  // persists across the mh pair within a kh

// mh=0 phase: read B(kh) into bfr + A(mh=0); MFMA quadrant 0
#define PH_B0(c, kh, S) do {                                                      \
    const char* Lb = lds + (c) * 65536 + (kh) * 16384;                            \
    s16x8 afr[4];                                                                 \
    _Pragma("unroll") for (int fn = 0; fn < 4; ++fn)                              \
      bfr[fn] = *reinterpret_cast<const s16x8*>(Lb + bRow + fn * 1024 + xslot);   \
    _Pragma("unroll") for (int fm = 0; fm < 4; ++fm)                              \
      afr[fm] = *reinterpret_cast<const s16x8*>(Lb + aRow + fm * 1024 + xslot);   \
    S;                                                                            \
    __builtin_amdgcn_s_barrier();                                                 \
    asm volatile("s_waitcnt lgkmcnt(0)" ::: "memory");                            \
    __builtin_amdgcn_sched_barrier(0);                                            \
    __builtin_amdgcn_s_setprio(1);                                                \
    _Pragma("unroll") for (int fm = 0; fm < 4; ++fm)                              \
      _Pragma("unroll") for (int fn = 0; fn < 4; ++fn)                            \
        acc[fm][fn] = __builtin_amdgcn_mfma_f32_16x16x32_bf16(                    \
            afr[fm], bfr[fn], acc[fm][fn], 0, 0, 0);                              \
    __builtin_amdgcn_s_setprio(0);                                                \
    __builtin_amdgcn_s_barrier();                                                 \
  } while (0)

// mh=1 phase: reuse bfr; read A(mh=1) only; MFMA quadrant 1
#define PH_A1(c, kh, S, WAIT) do {                                                \
    const char* Lb = lds + (c) * 65536 + (kh) * 16384;                            \
    s16x8 afr[4];                                                                 \
    _Pragma("unroll") for (int fm = 0; fm < 4; ++fm)                              \
      afr[fm] = *reinterpret_cast<const s16x8*>(Lb + aRow + 4096 + fm * 1024 + xslot); \
    S;                                                                            \
    __builtin_amdgcn_s_barrier();                                                 \
    asm volatile("s_waitcnt lgkmcnt(0)" ::: "memory");                            \
    __builtin_amdgcn_sched_barrier(0);                                            \
    __builtin_amdgcn_s_setprio(1);                                                \
    _Pragma("unroll") for (int fm = 0; fm < 4; ++fm)                              \
      _Pragma("unroll") for (int fn = 0; fn < 4; ++fn)                            \
        acc[4 + fm][fn] = __builtin_amdgcn_mfma_f32_16x16x32_bf16(                \
            afr[fm], bfr[fn], acc[4 + fm][fn], 0, 0, 0);                          \
    __builtin_amdgcn_s_setprio(0);                                                \
    WAIT;                                                                         \
    __builtin_amdgcn_s_barrier();                                                 \
  } while (0)

  // prologue: A0 -> buf0, A1 -> buf1 (reg path); B0,B1 via gload_lds
  ISSUE_H0(0); ISSUE_H1(0);
  VM0;
  AWRITE(0);
  ISSUE_H0(1); ISSUE_H1(1);
  STAGE_B(0, 0, 0); STAGE_B(0, 1, 0);
  STAGE_B(1, 0, 1); STAGE_B(1, 1, 1);
  VM8;                                               // A1 landed (B0,B1 in flight)
  AWRITE(1);
  VM4;                                               // B0 landed (B1 in flight = 4)
  asm volatile("s_waitcnt lgkmcnt(0)" ::: "memory"); // ds_writes done
  __builtin_amdgcn_s_barrier();

  // steady state at tile t start: ≤4 outstanding (B[t+1]); A[t],A[t+1] in LDS.
#pragma unroll 1
  for (int t = 0; t < 16; ++t) {
    const int c = t & 1;
    const int t2 = t + 2;
    PH_B0(c, 0, { if (t < 14) ISSUE_H0(t2); });
    PH_A1(c, 0, { if (t < 14) ISSUE_H1(t2); }, NW);
    PH_B0(c, 1, { if (t < 14) STAGE_B(t2, 0, c); });
    PH_A1(c, 1, { if (t < 14) STAGE_B(t2, 1, c); }, NW);
    if (t < 14) {        // VM4 leaves B[t+2](newest 4): A[t+2]+B[t+1] landed
      VM4;
      AWRITE(c);         // WAR-safe: all waves past tile t's buf-c A reads
    } else if (t == 14) {
      VM0;               // drain B[15]
    }
  }
#undef PH_B0
#undef PH_A1
#undef STAGE_B

  // epilogue: C/D layout col(fr)=o, row=(hi*4+reg)=s [verified]; per-(ot,wn) slab
  const int row0 = s_tile * 256 + wm * 128 + hi * 4;
  const int o0 = ot * 256 + wn * 64 + fr;
  const int bb = s_tile >> 3;

  float vv[4], wv[4], dv[4];
#pragma unroll
  for (int fn = 0; fn < 4; ++fn) {
    int o = o0 + fn * 16;
    vv[fn] = v[o];
    wv[fn] = wcov[o];
    dv[fn] = decf[bb * 1024 + o];
  }

  float* pout = part + (size_t)(ot * 4 + wn) * 65536;
#pragma unroll
  for (int i = 0; i < 8; ++i) {
#pragma unroll
    for (int r = 0; r < 4; ++r) {
      int s_flat = row0 + i * 16 + r;
      float cvv = cov[s_flat];
      float sum = 0.f;
#pragma unroll
      for (int fn = 0; fn < 4; ++fn) {
        float x = acc[i][fn][r] + dv[fn] + cvv * wv[fn];
        float xc = fminf(fmaxf(x, -15.f), 15.f);
        float e2 = __expf(2.f * xc);
        sum += (1.f - 2.f / (e2 + 1.f)) * vv[fn];  // tanh
      }
      sum += __shfl_xor(sum, 1, 64);
      sum += __shfl_xor(sum, 2, 64);
      sum += __shfl_xor(sum, 4, 64);
      sum += __shfl_xor(sum, 8, 64);
      if (fr == 0) pout[s_flat] = sum;
    }
  }
}

// ---- softmax over S=2048 per batch row; sums the 16 per-(ot,wn) partials ----
__global__ void softmax_kernel(const float* __restrict__ part, float* __restrict__ out) {
  int b = blockIdx.x;
  int tid = threadIdx.x;
  int lane = tid & 63, w = tid >> 6;
  float vals[8];
#pragma unroll
  for (int k = 0; k < 8; ++k) {
    int idx = b * Ss + tid + k * 256;
    float s0 = 0.f;
#pragma unroll
    for (int j = 0; j < 16; ++j) s0 += part[j * 65536 + idx];
    vals[k] = s0;
  }
  float m = vals[0];
#pragma unroll
  for (int k = 1; k < 8; ++k) m = fmaxf(m, vals[k]);
#pragma unroll
  for (int off = 1; off < 64; off <<= 1) m = fmaxf(m, __shfl_xor(m, off, 64));
  __shared__ float sm[4], ss[4];
  if (lane == 0) sm[w] = m;
  __syncthreads();
  m = fmaxf(fmaxf(sm[0], sm[1]), fmaxf(sm[2], sm[3]));
  float s = 0.f;
#pragma unroll
  for (int k = 0; k < 8; ++k) { vals[k] = __expf(vals[k] - m); s += vals[k]; }
#pragma unroll
  for (int off = 1; off < 64; off <<= 1) s += __shfl_xor(s, off, 64);
  if (lane == 0) ss[w] = s;
  __syncthreads();
  s = ss[0] + ss[1] + ss[2] + ss[3];
  float inv = 1.f / s;
#pragma unroll
  for (int k = 0; k < 8; ++k) out[(size_t)b * Ss + tid + k * 256] = vals[k] * inv;
}

extern "C" void kernel_launch(void* const* d_in, const int* in_sizes, int n_in,
                              void* d_out, int out_size, void* d_ws, size_t ws_size,
                              hipStream_t stream) {
  const float* dh    = (const float*)d_in[0];  // [32,1,1024]
  const float* enc   = (const float*)d_in[1];  // [32,2048,1024]
  const float* cov   = (const float*)d_in[2];  // [32,2048]
  const float* W_enc = (const float*)d_in[3];  // [1024,1024]
  const float* W_dec = (const float*)d_in[4];  // [1024,1024]
  const float* b_dec = (const float*)d_in[5];  // [1024]
  const float* w_cov = (const float*)d_in[6];  // [1024]
  const float* v     = (const float*)d_in[7];  // [1024]
  float* out = (float*)d_out;

  char* ws = (char*)d_ws;
  unsigned short* W_bf = (unsigned short*)ws;               // 2 MB tiled+swizzled
  float*          decf = (float*)(ws + 2097152);            // 128 KB
  float*          part = (float*)(ws + 2097152 + 131072);   // 4 MB partials [16][65536]

  cvt_w<<<512, 256, 0, stream>>>(W_enc, W_bf);
  dec_feat_kernel<<<(Bb * Hh) / 4, 256, 0, stream>>>(dh, W_dec, b_dec, decf);
  gemm8v<<<1024, 512, 0, stream>>>(enc, W_bf, decf, cov, w_cov, v, part);
  softmax_kernel<<<Bb, 256, 0, stream>>>(part, out);
}

// Round 13
// 254.488 us; speedup vs baseline: 1.0461x; 1.0461x over previous
//
#include <hip/hip_runtime.h>

#define Bb 32
#define Ss 2048
#define Hh 1024

typedef __attribute__((ext_vector_type(4))) float f32x4;
typedef __attribute__((ext_vector_type(8))) short s16x8;

#define GAS const __attribute__((address_space(1))) unsigned int
#define LAS __attribute__((address_space(3))) unsigned int

__device__ __forceinline__ unsigned short f2bf(float x) {
  unsigned int u = __float_as_uint(x);
  u = (u + 0x7fffu + ((u >> 16) & 1u)) >> 16;
  return (unsigned short)u;
}

// fp32 [rows][1024] -> bf16, tiled + inverse-swizzled (R8-verified layout):
// half = ((row>>8)*16 + kt)*2 + kh (16KB); byte = (row&255)*64 + ((k4^((r>>1)&3))<<4)
__global__ void cvt_swz(const float* __restrict__ in, unsigned short* __restrict__ out) {
  int g = blockIdx.x * blockDim.x + threadIdx.x;
  int row = g >> 7, k8 = g & 127;
  const float4* src = reinterpret_cast<const float4*>(in + (size_t)row * Hh + k8 * 8);
  float4 a = src[0], b = src[1];
  union { unsigned short u[8]; uint4 q; } rr;
  rr.u[0] = f2bf(a.x); rr.u[1] = f2bf(a.y); rr.u[2] = f2bf(a.z); rr.u[3] = f2bf(a.w);
  rr.u[4] = f2bf(b.x); rr.u[5] = f2bf(b.y); rr.u[6] = f2bf(b.z); rr.u[7] = f2bf(b.w);
  int kt = k8 >> 3, kh = (k8 >> 2) & 1, k4 = k8 & 3;
  int r = row & 255;
  size_t byte = (size_t)(((row >> 8) * 16 + kt) * 2 + kh) * 16384
              + (size_t)(r * 64 + ((k4 ^ ((r >> 1) & 3)) << 4));
  *reinterpret_cast<uint4*>(reinterpret_cast<char*>(out) + byte) = rr.q;
}

// ---- dec_feature[b][o] = dot(dh[b], W_dec[o]) + b_dec[o] ----
__global__ void dec_feat_kernel(const float* __restrict__ dh,
                                const float* __restrict__ Wd,
                                const float* __restrict__ bd,
                                float* __restrict__ out) {
  int gw = blockIdx.x * 4 + (threadIdx.x >> 6);
  int lane = threadIdx.x & 63;
  int b = gw >> 10, o = gw & 1023;
  const float4* x = reinterpret_cast<const float4*>(dh + (size_t)b * Hh);
  const float4* w = reinterpret_cast<const float4*>(Wd + (size_t)o * Hh);
  float acc = 0.f;
#pragma unroll
  for (int it = 0; it < 4; ++it) {
    float4 xa = x[lane + it * 64];
    float4 wa = w[lane + it * 64];
    acc += xa.x * wa.x + xa.y * wa.y + xa.z * wa.z + xa.w * wa.w;
  }
#pragma unroll
  for (int m = 1; m < 64; m <<= 1) acc += __shfl_xor(acc, m, 64);
  if (lane == 0) out[gw] = acc + bd[o];
}

// ---- 8-phase 256x256 GEMM (R8-verified skeleton) + B-frag reuse across mh ----
// 512 thr = 8 waves (2M x 4N), BK=64, 16 K-tiles, buf c = t&1.
// LDS buf: A-kh0 @0, A-kh1 @16K, B-kh0 @32K, B-kh1 @48K (64KB x 2).
// Phases (kh-major, mh-minor): mh=0 phase reads B(4)+A(4); mh=1 reuses bfr, reads A(4).
__global__ void __launch_bounds__(512, 2)
gemm8r(const unsigned short* __restrict__ Aw,  // tiled/swizzled bf16 [256 s_tiles]
       const unsigned short* __restrict__ Bw,  // tiled/swizzled bf16 [4 o_tiles]
       const float* __restrict__ decf,         // [32,1024]
       const float* __restrict__ cov,          // [32,2048]
       const float* __restrict__ wcov,         // [1024]
       const float* __restrict__ v,            // [1024]
       float* __restrict__ part) {             // [16][65536] partials (ot*4+wn)
  __shared__ char lds[131072];

  const int bid = blockIdx.x;
  const int swz = (bid & 7) * 128 + (bid >> 3);  // bijective: 1024 % 8 == 0
  const int s_tile = swz >> 2;  // 0..255
  const int ot = swz & 3;       // 0..3

  const int tid = threadIdx.x, lane = tid & 63, wid = tid >> 6;
  const int wm = wid >> 2, wn = wid & 3;     // per-wave out: 128 x 64
  const int fr = lane & 15, hi = lane >> 4;

  const char* gA = reinterpret_cast<const char*>(Aw) + (size_t)s_tile * 524288 + tid * 16;
  const char* gB = reinterpret_cast<const char*>(Bw) + (size_t)ot * 524288 + tid * 16;

  const int xslot = (hi ^ ((fr >> 1) & 3)) << 4;
  const int aRow = (wm * 128 + fr) * 64;            // + mh*4096 + fm*1024 + xslot
  const int bRow = 32768 + (wn * 64 + fr) * 64;     // + fn*1024 + xslot

  // stage half-tile stream H[j]: K-tile j>>2, h=j&3 (0:A-kh0 1:B-kh0 2:A-kh1 3:B-kh1)
#define STAGE(jj) do {                                                            \
    int _j = (jj);                                                                \
    if (_j < 64) {                                                                \
      int _kt = _j >> 2, _h = _j & 3, _isB = _h & 1, _kh = _h >> 1;               \
      const char* _src = (_isB ? gB : gA) + (size_t)(_kt * 2 + _kh) * 16384;      \
      char* _dst = lds + (_kt & 1) * 65536 + _isB * 32768 + _kh * 16384 + tid * 16; \
      __builtin_amdgcn_global_load_lds((GAS*)(_src),        (LAS*)(_dst),        16, 0, 0); \
      __builtin_amdgcn_global_load_lds((GAS*)(_src + 8192), (LAS*)(_dst + 8192), 16, 0, 0); \
    }                                                                             \
  } while (0)

#define NW ((void)0)
#define VM6 asm volatile("s_waitcnt vmcnt(6)" ::: "memory")
#define VM4 asm volatile("s_waitcnt vmcnt(4)" ::: "memory")
#define VM0 asm volatile("s_waitcnt vmcnt(0)" ::: "memory")
#define KWAIT(t) do { if ((t) < 14) VM4; else if ((t) == 14) VM0; } while (0)

  f32x4 acc[8][4];
#pragma unroll
  for (int i = 0; i < 8; ++i)
#pragma unroll
    for (int j = 0; j < 4; ++j) acc[i][j] = (f32x4){0.f, 0.f, 0.f, 0.f};

  s16x8 bfr[4];  // persists across the mh pair within a kh

// mh=0 phase: read B(kh) into bfr + A(mh=0); MFMA quadrant 0
#define PH_B0(c, kh, jj, WAIT) do {                                               \
    const char* Lb = lds + (c) * 65536 + (kh) * 16384;                            \
    s16x8 afr[4];                                                                 \
    _Pragma("unroll") for (int fn = 0; fn < 4; ++fn)                              \
      bfr[fn] = *reinterpret_cast<const s16x8*>(Lb + bRow + fn * 1024 + xslot);   \
    _Pragma("unroll") for (int fm = 0; fm < 4; ++fm)                              \
      afr[fm] = *reinterpret_cast<const s16x8*>(Lb + aRow + fm * 1024 + xslot);   \
    STAGE(jj);                                                                    \
    __builtin_amdgcn_s_barrier();                                                 \
    asm volatile("s_waitcnt lgkmcnt(0)" ::: "memory");                            \
    __builtin_amdgcn_sched_barrier(0);                                            \
    __builtin_amdgcn_s_setprio(1);                                                \
    _Pragma("unroll") for (int fm = 0; fm < 4; ++fm)                              \
      _Pragma("unroll") for (int fn = 0; fn < 4; ++fn)                            \
        acc[fm][fn] = __builtin_amdgcn_mfma_f32_16x16x32_bf16(                    \
            afr[fm], bfr[fn], acc[fm][fn], 0, 0, 0);                              \
    __builtin_amdgcn_s_setprio(0);                                                \
    WAIT;                                                                         \
    __builtin_amdgcn_s_barrier();                                                 \
  } while (0)

// mh=1 phase: reuse bfr; read A(mh=1) only; MFMA quadrant 1
#define PH_A1(c, kh, jj, WAIT) do {                                               \
    const char* Lb = lds + (c) * 65536 + (kh) * 16384;                            \
    s16x8 afr[4];                                                                 \
    _Pragma("unroll") for (int fm = 0; fm < 4; ++fm)                              \
      afr[fm] = *reinterpret_cast<const s16x8*>(Lb + aRow + 4096 + fm * 1024 + xslot); \
    STAGE(jj);                                                                    \
    __builtin_amdgcn_s_barrier();                                                 \
    asm volatile("s_waitcnt lgkmcnt(0)" ::: "memory");                            \
    __builtin_amdgcn_sched_barrier(0);                                            \
    __builtin_amdgcn_s_setprio(1);                                                \
    _Pragma("unroll") for (int fm = 0; fm < 4; ++fm)                              \
      _Pragma("unroll") for (int fn = 0; fn < 4; ++fn)                            \
        acc[4 + fm][fn] = __builtin_amdgcn_mfma_f32_16x16x32_bf16(                \
            afr[fm], bfr[fn], acc[4 + fm][fn], 0, 0, 0);                          \
    __builtin_amdgcn_s_setprio(0);                                                \
    WAIT;                                                                         \
    __builtin_amdgcn_s_barrier();                                                 \
  } while (0)

  // prologue: halves 0-6 (K0 complete + K1 A-kh0,B-kh0,A-kh1); wait K0 landed
  STAGE(0); STAGE(1); STAGE(2); STAGE(3); STAGE(4); STAGE(5); STAGE(6);
  VM6;
  __builtin_amdgcn_s_barrier();

#pragma unroll 1
  for (int t = 0; t < 16; ++t) {
    const int c = t & 1;
    const int j0 = 4 * t + 7;
    PH_B0(c, 0, j0,     NW);        // stages K[t+1].B-kh1
    PH_A1(c, 0, j0 + 1, NW);        // stages K[t+2].A-kh0
    PH_B0(c, 1, j0 + 2, NW);        // stages K[t+2].B-kh0
    PH_A1(c, 1, j0 + 3, KWAIT(t));  // stages K[t+2].A-kh1; tile-boundary wait
  }
#undef PH_B0
#undef PH_A1
#undef STAGE

  // epilogue: C/D layout col(fr)=o, row=(hi*4+reg)=s [verified]; per-(ot,wn) slab
  const int row0 = s_tile * 256 + wm * 128 + hi * 4;
  const int o0 = ot * 256 + wn * 64 + fr;
  const int bb = s_tile >> 3;

  float vv[4], wv[4], dv[4];
#pragma unroll
  for (int fn = 0; fn < 4; ++fn) {
    int o = o0 + fn * 16;
    vv[fn] = v[o];
    wv[fn] = wcov[o];
    dv[fn] = decf[bb * 1024 + o];
  }

  float* pout = part + (size_t)(ot * 4 + wn) * 65536;
#pragma unroll
  for (int i = 0; i < 8; ++i) {
#pragma unroll
    for (int r = 0; r < 4; ++r) {
      int s_flat = row0 + i * 16 + r;
      float cvv = cov[s_flat];
      float sum = 0.f;
#pragma unroll
      for (int fn = 0; fn < 4; ++fn) {
        float x = acc[i][fn][r] + dv[fn] + cvv * wv[fn];
        float xc = fminf(fmaxf(x, -15.f), 15.f);
        float e2 = __expf(2.f * xc);
        sum += (1.f - 2.f / (e2 + 1.f)) * vv[fn];  // tanh
      }
      sum += __shfl_xor(sum, 1, 64);
      sum += __shfl_xor(sum, 2, 64);
      sum += __shfl_xor(sum, 4, 64);
      sum += __shfl_xor(sum, 8, 64);
      if (fr == 0) pout[s_flat] = sum;
    }
  }
}

// ---- softmax over S=2048 per batch row; sums the 16 per-(ot,wn) partials ----
__global__ void softmax_kernel(const float* __restrict__ part, float* __restrict__ out) {
  int b = blockIdx.x;
  int tid = threadIdx.x;
  int lane = tid & 63, w = tid >> 6;
  float vals[8];
#pragma unroll
  for (int k = 0; k < 8; ++k) {
    int idx = b * Ss + tid + k * 256;
    float s0 = 0.f;
#pragma unroll
    for (int j = 0; j < 16; ++j) s0 += part[j * 65536 + idx];
    vals[k] = s0;
  }
  float m = vals[0];
#pragma unroll
  for (int k = 1; k < 8; ++k) m = fmaxf(m, vals[k]);
#pragma unroll
  for (int off = 1; off < 64; off <<= 1) m = fmaxf(m, __shfl_xor(m, off, 64));
  __shared__ float sm[4], ss[4];
  if (lane == 0) sm[w] = m;
  __syncthreads();
  m = fmaxf(fmaxf(sm[0], sm[1]), fmaxf(sm[2], sm[3]));
  float s = 0.f;
#pragma unroll
  for (int k = 0; k < 8; ++k) { vals[k] = __expf(vals[k] - m); s += vals[k]; }
#pragma unroll
  for (int off = 1; off < 64; off <<= 1) s += __shfl_xor(s, off, 64);
  if (lane == 0) ss[w] = s;
  __syncthreads();
  s = ss[0] + ss[1] + ss[2] + ss[3];
  float inv = 1.f / s;
#pragma unroll
  for (int k = 0; k < 8; ++k) out[(size_t)b * Ss + tid + k * 256] = vals[k] * inv;
}

extern "C" void kernel_launch(void* const* d_in, const int* in_sizes, int n_in,
                              void* d_out, int out_size, void* d_ws, size_t ws_size,
                              hipStream_t stream) {
  const float* dh    = (const float*)d_in[0];  // [32,1,1024]
  const float* enc   = (const float*)d_in[1];  // [32,2048,1024]
  const float* cov   = (const float*)d_in[2];  // [32,2048]
  const float* W_enc = (const float*)d_in[3];  // [1024,1024]
  const float* W_dec = (const float*)d_in[4];  // [1024,1024]
  const float* b_dec = (const float*)d_in[5];  // [1024]
  const float* w_cov = (const float*)d_in[6];  // [1024]
  const float* v     = (const float*)d_in[7];  // [1024]
  float* out = (float*)d_out;

  char* ws = (char*)d_ws;
  unsigned short* A_bf  = (unsigned short*)ws;                   // 128 MB tiled+swizzled
  unsigned short* W_bf  = (unsigned short*)(ws + 134217728);     // 2 MB tiled+swizzled
  float*          decf  = (float*)(ws + 136314880);              // 128 KB
  float*          part  = (float*)(ws + 136445952);              // 4 MB partials [16][65536]

  cvt_swz<<<32768, 256, 0, stream>>>(enc, A_bf);    // 65536 rows
  cvt_swz<<<512, 256, 0, stream>>>(W_enc, W_bf);    // 1024 rows
  dec_feat_kernel<<<(Bb * Hh) / 4, 256, 0, stream>>>(dh, W_dec, b_dec, decf);
  gemm8r<<<1024, 512, 0, stream>>>(A_bf, W_bf, decf, cov, w_cov, v, part);
  softmax_kernel<<<Bb, 256, 0, stream>>>(part, out);
}

// Round 15
// 252.650 us; speedup vs baseline: 1.0537x; 1.0073x over previous
//
#include <hip/hip_runtime.h>

#define Bb 32
#define Ss 2048
#define Hh 1024

typedef __attribute__((ext_vector_type(4))) float f32x4;
typedef __attribute__((ext_vector_type(8))) short s16x8;

#define GAS const __attribute__((address_space(1))) unsigned int
#define LAS __attribute__((address_space(3))) unsigned int

__device__ __forceinline__ unsigned short f2bf(float x) {
  unsigned int u = __float_as_uint(x);
  u = (u + 0x7fffu + ((u >> 16) & 1u)) >> 16;
  return (unsigned short)u;
}

// fp32 [rows][1024] -> bf16, tiled + inverse-swizzled (R8-verified layout):
// half = ((row>>8)*16 + kt)*2 + kh (16KB); byte = (row&255)*64 + ((k4^((r>>1)&3))<<4)
__global__ void cvt_swz(const float* __restrict__ in, unsigned short* __restrict__ out) {
  int g = blockIdx.x * blockDim.x + threadIdx.x;
  int row = g >> 7, k8 = g & 127;
  const float4* src = reinterpret_cast<const float4*>(in + (size_t)row * Hh + k8 * 8);
  float4 a = src[0], b = src[1];
  union { unsigned short u[8]; uint4 q; } rr;
  rr.u[0] = f2bf(a.x); rr.u[1] = f2bf(a.y); rr.u[2] = f2bf(a.z); rr.u[3] = f2bf(a.w);
  rr.u[4] = f2bf(b.x); rr.u[5] = f2bf(b.y); rr.u[6] = f2bf(b.z); rr.u[7] = f2bf(b.w);
  int kt = k8 >> 3, kh = (k8 >> 2) & 1, k4 = k8 & 3;
  int r = row & 255;
  size_t byte = (size_t)(((row >> 8) * 16 + kt) * 2 + kh) * 16384
              + (size_t)(r * 64 + ((k4 ^ ((r >> 1) & 3)) << 4));
  *reinterpret_cast<uint4*>(reinterpret_cast<char*>(out) + byte) = rr.q;
}

// ---- dec_feature[b][o] = dot(dh[b], W_dec[o]) + b_dec[o] ----
__global__ void dec_feat_kernel(const float* __restrict__ dh,
                                const float* __restrict__ Wd,
                                const float* __restrict__ bd,
                                float* __restrict__ out) {
  int gw = blockIdx.x * 4 + (threadIdx.x >> 6);
  int lane = threadIdx.x & 63;
  int b = gw >> 10, o = gw & 1023;
  const float4* x = reinterpret_cast<const float4*>(dh + (size_t)b * Hh);
  const float4* w = reinterpret_cast<const float4*>(Wd + (size_t)o * Hh);
  float acc = 0.f;
#pragma unroll
  for (int it = 0; it < 4; ++it) {
    float4 xa = x[lane + it * 64];
    float4 wa = w[lane + it * 64];
    acc += xa.x * wa.x + xa.y * wa.y + xa.z * wa.z + xa.w * wa.w;
  }
#pragma unroll
  for (int m = 1; m < 64; m <<= 1) acc += __shfl_xor(acc, m, 64);
  if (lane == 0) out[gw] = acc + bd[o];
}

// ---- 2-phase-per-tile 256x256 GEMM, race-free stage placement ----
// 512 thr = 8 waves (2M x 4N), BK=64, 16 K-tiles, buf c = t&1.
// LDS buf: A-kh0 @0, A-kh1 @16K, B-kh0 @32K, B-kh1 @48K (64KB x 2).
// ph1 (mh0): read B both kh (held in regs) + A-mh0 (16 rds); stage A[t+1]->buf c^1
//            (no region of buf c^1 is read during tile t -> zero WAR exposure).
// ph2 (mh1): read A-mh1 (8 rds); stage B[t+2]->buf c (B readers done at ph1 barrier);
//            tile-end vmcnt(4) -> A[t+1], B[t+1] landed.
__global__ void __launch_bounds__(512, 2)
gemm2p(const unsigned short* __restrict__ Aw,  // tiled/swizzled bf16 [256 s_tiles]
       const unsigned short* __restrict__ Bw,  // tiled/swizzled bf16 [4 o_tiles]
       const float* __restrict__ decf,         // [32,1024]
       const float* __restrict__ cov,          // [32,2048]
       const float* __restrict__ wcov,         // [1024]
       const float* __restrict__ v,            // [1024]
       float* __restrict__ part) {             // [16][65536] partials (ot*4+wn)
  __shared__ char lds[131072];

  const int bid = blockIdx.x;
  const int swz = (bid & 7) * 128 + (bid >> 3);  // bijective: 1024 % 8 == 0
  const int s_tile = swz >> 2;  // 0..255
  const int ot = swz & 3;       // 0..3

  const int tid = threadIdx.x, lane = tid & 63, wid = tid >> 6;
  const int wm = wid >> 2, wn = wid & 3;     // per-wave out: 128 x 64
  const int fr = lane & 15, hi = lane >> 4;

  const char* gA = reinterpret_cast<const char*>(Aw) + (size_t)s_tile * 524288 + tid * 16;
  const char* gB = reinterpret_cast<const char*>(Bw) + (size_t)ot * 524288 + tid * 16;

  const int xslot = (hi ^ ((fr >> 1) & 3)) << 4;
  const int aRow = (wm * 128 + fr) * 64;            // + mh*4096 + fm*1024 + xslot
  const int bRow = (wn * 64 + fr) * 64;             // + fn*1024 + xslot (B-region rel)

// stage BOTH kh of A[tt] into buf (tt)&1 (A region: bytes 0..32K, contiguous kh0|kh1)
#define STAGE_A2(tt) do {                                                         \
    const char* _s = gA + (size_t)(tt) * 32768;                                   \
    char* _d = lds + ((tt) & 1) * 65536 + tid * 16;                               \
    __builtin_amdgcn_global_load_lds((GAS*)(_s),         (LAS*)(_d),         16, 0, 0); \
    __builtin_amdgcn_global_load_lds((GAS*)(_s + 8192),  (LAS*)(_d + 8192),  16, 0, 0); \
    __builtin_amdgcn_global_load_lds((GAS*)(_s + 16384), (LAS*)(_d + 16384), 16, 0, 0); \
    __builtin_amdgcn_global_load_lds((GAS*)(_s + 24576), (LAS*)(_d + 24576), 16, 0, 0); \
  } while (0)
// stage BOTH kh of B[tt] into buf (tt)&1 (B region: bytes 32K..64K)
#define STAGE_B2(tt) do {                                                         \
    const char* _s = gB + (size_t)(tt) * 32768;                                   \
    char* _d = lds + ((tt) & 1) * 65536 + 32768 + tid * 16;                       \
    __builtin_amdgcn_global_load_lds((GAS*)(_s),         (LAS*)(_d),         16, 0, 0); \
    __builtin_amdgcn_global_load_lds((GAS*)(_s + 8192),  (LAS*)(_d + 8192),  16, 0, 0); \
    __builtin_amdgcn_global_load_lds((GAS*)(_s + 16384), (LAS*)(_d + 16384), 16, 0, 0); \
    __builtin_amdgcn_global_load_lds((GAS*)(_s + 24576), (LAS*)(_d + 24576), 16, 0, 0); \
  } while (0)

#define VM4 asm volatile("s_waitcnt vmcnt(4)" ::: "memory")
#define VM0 asm volatile("s_waitcnt vmcnt(0)" ::: "memory")

  f32x4 acc[8][4];
#pragma unroll
  for (int i = 0; i < 8; ++i)
#pragma unroll
    for (int j = 0; j < 4; ++j) acc[i][j] = (f32x4){0.f, 0.f, 0.f, 0.f};

  s16x8 bfr[2][4];  // B fragments, both kh, held across the phase pair

  // prologue: A[0],B[0],B[1] (12 loads); VM4 -> A[0],B[0] landed (B[1] in flight)
  STAGE_A2(0); STAGE_B2(0); STAGE_B2(1);
  VM4;
  __builtin_amdgcn_s_barrier();

#pragma unroll 1
  for (int t = 0; t < 16; ++t) {
    const int c = t & 1;
    const char* LA0 = lds + c * 65536;
    const char* LA1 = LA0 + 16384;
    const char* LB0 = LA0 + 32768;
    const char* LB1 = LA0 + 49152;

    // ---- phase 1: mh=0; stage A[t+1] -> buf c^1 (not read this tile) ----
    {
      s16x8 af0[4], af1[4];
#pragma unroll
      for (int fn = 0; fn < 4; ++fn) {
        bfr[0][fn] = *reinterpret_cast<const s16x8*>(LB0 + bRow + fn * 1024 + xslot);
        bfr[1][fn] = *reinterpret_cast<const s16x8*>(LB1 + bRow + fn * 1024 + xslot);
      }
#pragma unroll
      for (int fm = 0; fm < 4; ++fm) {
        af0[fm] = *reinterpret_cast<const s16x8*>(LA0 + aRow + fm * 1024 + xslot);
        af1[fm] = *reinterpret_cast<const s16x8*>(LA1 + aRow + fm * 1024 + xslot);
      }
      if (t < 15) STAGE_A2(t + 1);
      __builtin_amdgcn_s_barrier();
      asm volatile("s_waitcnt lgkmcnt(0)" ::: "memory");
      __builtin_amdgcn_sched_barrier(0);
      __builtin_amdgcn_s_setprio(1);
#pragma unroll
      for (int fm = 0; fm < 4; ++fm)
#pragma unroll
        for (int fn = 0; fn < 4; ++fn) {
          acc[fm][fn] = __builtin_amdgcn_mfma_f32_16x16x32_bf16(
              af0[fm], bfr[0][fn], acc[fm][fn], 0, 0, 0);
          acc[fm][fn] = __builtin_amdgcn_mfma_f32_16x16x32_bf16(
              af1[fm], bfr[1][fn], acc[fm][fn], 0, 0, 0);
        }
      __builtin_amdgcn_s_setprio(0);
      __builtin_amdgcn_s_barrier();
    }

    // ---- phase 2: mh=1 (reuse bfr); stage B[t+2] -> buf c (B reads done) ----
    {
      s16x8 af0[4], af1[4];
#pragma unroll
      for (int fm = 0; fm < 4; ++fm) {
        af0[fm] = *reinterpret_cast<const s16x8*>(LA0 + aRow + 4096 + fm * 1024 + xslot);
        af1[fm] = *reinterpret_cast<const s16x8*>(LA1 + aRow + 4096 + fm * 1024 + xslot);
      }
      if (t < 14) STAGE_B2(t + 2);
      __builtin_amdgcn_s_barrier();
      asm volatile("s_waitcnt lgkmcnt(0)" ::: "memory");
      __builtin_amdgcn_sched_barrier(0);
      __builtin_amdgcn_s_setprio(1);
#pragma unroll
      for (int fm = 0; fm < 4; ++fm)
#pragma unroll
        for (int fn = 0; fn < 4; ++fn) {
          acc[4 + fm][fn] = __builtin_amdgcn_mfma_f32_16x16x32_bf16(
              af0[fm], bfr[0][fn], acc[4 + fm][fn], 0, 0, 0);
          acc[4 + fm][fn] = __builtin_amdgcn_mfma_f32_16x16x32_bf16(
              af1[fm], bfr[1][fn], acc[4 + fm][fn], 0, 0, 0);
        }
      __builtin_amdgcn_s_setprio(0);
      if (t < 14) { VM4; } else if (t == 14) { VM0; }
      __builtin_amdgcn_s_barrier();
    }
  }
#undef STAGE_A2
#undef STAGE_B2

  // epilogue: C/D layout col(fr)=o, row=(hi*4+reg)=s [verified]; per-(ot,wn) slab
  const int row0 = s_tile * 256 + wm * 128 + hi * 4;
  const int o0 = ot * 256 + wn * 64 + fr;
  const int bb = s_tile >> 3;

  float vv[4], wv[4], dv[4];
#pragma unroll
  for (int fn = 0; fn < 4; ++fn) {
    int o = o0 + fn * 16;
    vv[fn] = v[o];
    wv[fn] = wcov[o];
    dv[fn] = decf[bb * 1024 + o];
  }

  float* pout = part + (size_t)(ot * 4 + wn) * 65536;
#pragma unroll
  for (int i = 0; i < 8; ++i) {
#pragma unroll
    for (int r = 0; r < 4; ++r) {
      int s_flat = row0 + i * 16 + r;
      float cvv = cov[s_flat];
      float sum = 0.f;
#pragma unroll
      for (int fn = 0; fn < 4; ++fn) {
        float x = acc[i][fn][r] + dv[fn] + cvv * wv[fn];
        float xc = fminf(fmaxf(x, -15.f), 15.f);
        float e2 = __expf(2.f * xc);
        sum += (1.f - 2.f / (e2 + 1.f)) * vv[fn];  // tanh
      }
      sum += __shfl_xor(sum, 1, 64);
      sum += __shfl_xor(sum, 2, 64);
      sum += __shfl_xor(sum, 4, 64);
      sum += __shfl_xor(sum, 8, 64);
      if (fr == 0) pout[s_flat] = sum;
    }
  }
}

// ---- softmax over S=2048 per batch row; sums the 16 per-(ot,wn) partials ----
__global__ void softmax_kernel(const float* __restrict__ part, float* __restrict__ out) {
  int b = blockIdx.x;
  int tid = threadIdx.x;
  int lane = tid & 63, w = tid >> 6;
  float vals[8];
#pragma unroll
  for (int k = 0; k < 8; ++k) {
    int idx = b * Ss + tid + k * 256;
    float s0 = 0.f;
#pragma unroll
    for (int j = 0; j < 16; ++j) s0 += part[j * 65536 + idx];
    vals[k] = s0;
  }
  float m = vals[0];
#pragma unroll
  for (int k = 1; k < 8; ++k) m = fmaxf(m, vals[k]);
#pragma unroll
  for (int off = 1; off < 64; off <<= 1) m = fmaxf(m, __shfl_xor(m, off, 64));
  __shared__ float sm[4], ss[4];
  if (lane == 0) sm[w] = m;
  __syncthreads();
  m = fmaxf(fmaxf(sm[0], sm[1]), fmaxf(sm[2], sm[3]));
  float s = 0.f;
#pragma unroll
  for (int k = 0; k < 8; ++k) { vals[k] = __expf(vals[k] - m); s += vals[k]; }
#pragma unroll
  for (int off = 1; off < 64; off <<= 1) s += __shfl_xor(s, off, 64);
  if (lane == 0) ss[w] = s;
  __syncthreads();
  s = ss[0] + ss[1] + ss[2] + ss[3];
  float inv = 1.f / s;
#pragma unroll
  for (int k = 0; k < 8; ++k) out[(size_t)b * Ss + tid + k * 256] = vals[k] * inv;
}

extern "C" void kernel_launch(void* const* d_in, const int* in_sizes, int n_in,
                              void* d_out, int out_size, void* d_ws, size_t ws_size,
                              hipStream_t stream) {
  const float* dh    = (const float*)d_in[0];  // [32,1,1024]
  const float* enc   = (const float*)d_in[1];  // [32,2048,1024]
  const float* cov   = (const float*)d_in[2];  // [32,2048]
  const float* W_enc = (const float*)d_in[3];  // [1024,1024]
  const float* W_dec = (const float*)d_in[4];  // [1024,1024]
  const float* b_dec = (const float*)d_in[5];  // [1024]
  const float* w_cov = (const float*)d_in[6];  // [1024]
  const float* v     = (const float*)d_in[7];  // [1024]
  float* out = (float*)d_out;

  char* ws = (char*)d_ws;
  unsigned short* A_bf  = (unsigned short*)ws;                   // 128 MB tiled+swizzled
  unsigned short* W_bf  = (unsigned short*)(ws + 134217728);     // 2 MB tiled+swizzled
  float*          decf  = (float*)(ws + 136314880);              // 128 KB
  float*          part  = (float*)(ws + 136445952);              // 4 MB partials [16][65536]

  cvt_swz<<<32768, 256, 0, stream>>>(enc, A_bf);    // 65536 rows
  cvt_swz<<<512, 256, 0, stream>>>(W_enc, W_bf);    // 1024 rows
  dec_feat_kernel<<<(Bb * Hh) / 4, 256, 0, stream>>>(dh, W_dec, b_dec, decf);
  gemm2p<<<1024, 512, 0, stream>>>(A_bf, W_bf, decf, cov, w_cov, v, part);
  softmax_kernel<<<Bb, 256, 0, stream>>>(part, out);
}